// Round 4
// baseline (8963.543 us; speedup 1.0000x reference)
//
#include <hip/hip_runtime.h>
#include <hip/hip_bf16.h>

// ============================================================================
// Stacked-LSTM LM on MI355X — round 3 (resubmit; round lost to GPU timeout).
//   Round-2 failure mode: __threadfence() (L2 wb/inv) every phase kept L2
//   permanently cold + µs-scale fence cost -> 22.7 µs/phase, all pipes idle.
//   Fix: NO fences at all. Cross-block h-state via relaxed agent-scope
//   atomics (sc-flagged, L2-bypassing). Weights/esw/x plain loads -> L2 stays
//   warm. Block-private state (c, seq, prev-out) plain ops on own XCD L2.
//   Barrier: single monotonic relaxed counter, spin >= 64*(p+1).
//   64 blocks x 512 thr; block owns 16 units/layer; waves=(lay,khalf,rowhalf).
// ws: WA|WB|Wd1F|Wd2F|esw|h1b[2]|h2b[2]|c1|c2|seq|hd|bar  (~105 MB)
// ============================================================================

#define DI __device__ __forceinline__

typedef __attribute__((ext_vector_type(8))) short s8v;   // 8 x bf16 bits
typedef __attribute__((ext_vector_type(4))) float f4v;   // MFMA accumulator

DI f4v mfma16(s8v a, s8v b, f4v c){
  return __builtin_amdgcn_mfma_f32_16x16x32_bf16(a, b, c, 0, 0, 0);
}
DI s8v as_s8(uint4 u){ return __builtin_bit_cast(s8v, u); }

DI unsigned short f2b(float f){            // fp32 -> bf16 bits, RNE
  unsigned u = __float_as_uint(f);
  u = u + 0x7fffu + ((u >> 16) & 1u);
  return (unsigned short)(u >> 16);
}
DI float b2f(unsigned short h){ return __uint_as_float(((unsigned)h) << 16); }
DI float sig_(float x){ return 1.f / (1.f + __expf(-x)); }
DI float tanh_(float x){ return 1.f - 2.f / (__expf(2.f * x) + 1.f); }

// 16B coherent (agent-scope, L2-bypass) load as 2x8B relaxed atomics.
DI uint4 ldA(const unsigned long long* p){
  unsigned long long lo = __hip_atomic_load(p,     __ATOMIC_RELAXED, __HIP_MEMORY_SCOPE_AGENT);
  unsigned long long hi = __hip_atomic_load(p + 1, __ATOMIC_RELAXED, __HIP_MEMORY_SCOPE_AGENT);
  uint4 r; r.x = (unsigned)lo; r.y = (unsigned)(lo >> 32);
  r.z = (unsigned)hi; r.w = (unsigned)(hi >> 32);
  return r;
}
DI unsigned short ldH(const unsigned short* p){
  return __hip_atomic_load(p, __ATOMIC_RELAXED, __HIP_MEMORY_SCOPE_AGENT);
}
DI void stH(unsigned short* p, unsigned short v){
  __hip_atomic_store(p, v, __ATOMIC_RELAXED, __HIP_MEMORY_SCOPE_AGENT);
}

// ---------------------------------------------------------------------------
// Setup kernels (unchanged)
// ---------------------------------------------------------------------------
__global__ __launch_bounds__(256) void k_pack_AB(const float* __restrict__ Wx,
                                                 const float* __restrict__ Ux,
                                                 unsigned short* __restrict__ dst,
                                                 int KS, int kx){
  int idx = blockIdx.x * 256 + threadIdx.x;
  if (idx >= 256 * KS * 64) return;
  int l = idx & 63, rest = idx >> 6;
  int ks = rest % KS, b = rest / KS;
  int c = l & 15;
  int col = 4 * b + (c & 3) + ((c >> 2) << 10);
  int k0 = ks * 32 + ((l >> 4) << 3);
  const float* src = (k0 < kx) ? (Wx + (size_t)k0 * 4096)
                               : (Ux + (size_t)(k0 - kx) * 4096);
  unsigned v[4];
  #pragma unroll
  for (int p = 0; p < 4; ++p){
    unsigned short lo = f2b(src[(size_t)(2 * p) * 4096 + col]);
    unsigned short hi = f2b(src[(size_t)(2 * p + 1) * 4096 + col]);
    v[p] = (unsigned)lo | ((unsigned)hi << 16);
  }
  uint4 o; o.x = v[0]; o.y = v[1]; o.z = v[2]; o.w = v[3];
  ((uint4*)dst)[idx] = o;
}

__global__ __launch_bounds__(256) void k_pack_D(const float* __restrict__ W,
                                                unsigned short* __restrict__ dst,
                                                int CG, int N){
  int idx = blockIdx.x * 256 + threadIdx.x;
  if (idx >= CG * 32 * 64) return;
  int l = idx & 63;
  int ks = (idx >> 6) & 31;
  int cg = idx >> 11;
  int col = 16 * cg + (l & 15);
  int k0 = 32 * ks + ((l >> 4) << 3);
  unsigned v[4];
  #pragma unroll
  for (int p = 0; p < 4; ++p){
    unsigned short lo = f2b(W[(size_t)(k0 + 2 * p) * N + col]);
    unsigned short hi = f2b(W[(size_t)(k0 + 2 * p + 1) * N + col]);
    v[p] = (unsigned)lo | ((unsigned)hi << 16);
  }
  uint4 o; o.x = v[0]; o.y = v[1]; o.z = v[2]; o.w = v[3];
  ((uint4*)dst)[idx] = o;
}

__global__ __launch_bounds__(256) void k_embed(const int* __restrict__ x,
                                               const float* __restrict__ emb,
                                               unsigned short* __restrict__ dst){
  int idx = blockIdx.x * 256 + threadIdx.x;
  int l = idx & 63;
  int w = (idx >> 6) & 3;
  int ks = (idx >> 8) & 7;
  int t = idx >> 11;
  int row = 16 * w + (l & 15);
  int xi = x[row * 256 + t];
  int k0 = 32 * ks + ((l >> 4) << 3);
  const float* src = emb + (size_t)xi * 256 + k0;
  unsigned v[4];
  #pragma unroll
  for (int p = 0; p < 4; ++p){
    unsigned short lo = f2b(src[2 * p]);
    unsigned short hi = f2b(src[2 * p + 1]);
    v[p] = (unsigned)lo | ((unsigned)hi << 16);
  }
  uint4 o; o.x = v[0]; o.y = v[1]; o.z = v[2]; o.w = v[3];
  ((uint4*)dst)[idx] = o;
}

// ---------------------------------------------------------------------------
// Persistent scan: 64 blocks x 512 threads (8 waves).
// Wave w: lay=w>>2 (0:L1, 1:L2), kh=(w>>1)&1 (K half), rh=w&1 (rows 32*rh..).
// Block owns z-col-groups cg = 4*blk..4*blk+3 per layer (16 units each layer).
// Phase p: L1 step t=p (p<256) || L2 step t=p-1 (p>=1). 256 barriers.
// ---------------------------------------------------------------------------
__global__ __launch_bounds__(512, 2) void k_scan(
    const unsigned short* __restrict__ esw,
    const unsigned short* __restrict__ WA,
    const unsigned short* __restrict__ WB,
    const float* __restrict__ b1v, const float* __restrict__ b2v,
    const int* __restrict__ x,
    unsigned short* __restrict__ h1b, unsigned short* __restrict__ h2b,
    float* __restrict__ c1, float* __restrict__ c2,
    unsigned short* __restrict__ seq, int* __restrict__ bar){
  __shared__ float red[2][2][2][4][2][64][4];  // [lay][kh][rh][ct][rtl][l][q] 64KB
  const int blk = blockIdx.x, tid = threadIdx.x;
  const int w = tid >> 6, l = tid & 63;
  const int lay = w >> 2, kh = (w >> 1) & 1, rh = w & 1;
  const int rt0 = 2 * rh;
  const int cg0 = 4 * blk;
  const uint4* WAu  = (const uint4*)WA;
  const uint4* WBu  = (const uint4*)WB;
  const uint4* eswU = (const uint4*)esw;
  const int c = l & 15, u = c & 3, g = c >> 2;

  #pragma unroll 1
  for (int p = 0; p <= 256; ++p){
    const int par = p & 1;
    f4v acc[2][4];
    #pragma unroll
    for (int i = 0; i < 2; ++i)
      #pragma unroll
      for (int j = 0; j < 4; ++j) acc[i][j] = (f4v){0.f, 0.f, 0.f, 0.f};

    if (lay == 0){
      if (p < 256){
        const uint4* eswT = eswU + (size_t)p * 2048;
        const unsigned long long* h1i =
            (const unsigned long long*)(h1b + (size_t)par * 65536);
        if (kh == 0){
          #pragma unroll 2
          for (int ks = 0; ks < 8; ++ks){          // embedding part (plain, L2)
            uint4 a0 = eswT[(ks * 4 + rt0    ) * 64 + l];
            uint4 a1 = eswT[(ks * 4 + rt0 + 1) * 64 + l];
            #pragma unroll
            for (int ct = 0; ct < 4; ++ct){
              uint4 b = WAu[(((size_t)(cg0 + ct)) * 40 + ks) * 64 + l];
              acc[0][ct] = mfma16(as_s8(a0), as_s8(b), acc[0][ct]);
              acc[1][ct] = mfma16(as_s8(a1), as_s8(b), acc[1][ct]);
            }
          }
          #pragma unroll 4
          for (int kk = 0; kk < 12; ++kk){         // h1 part (coherent)
            uint4 a0 = ldA(h1i + (size_t)((kk * 4 + rt0    ) * 64 + l) * 2);
            uint4 a1 = ldA(h1i + (size_t)((kk * 4 + rt0 + 1) * 64 + l) * 2);
            #pragma unroll
            for (int ct = 0; ct < 4; ++ct){
              uint4 b = WAu[(((size_t)(cg0 + ct)) * 40 + kk + 8) * 64 + l];
              acc[0][ct] = mfma16(as_s8(a0), as_s8(b), acc[0][ct]);
              acc[1][ct] = mfma16(as_s8(a1), as_s8(b), acc[1][ct]);
            }
          }
        } else {
          #pragma unroll 4
          for (int kk = 12; kk < 32; ++kk){
            uint4 a0 = ldA(h1i + (size_t)((kk * 4 + rt0    ) * 64 + l) * 2);
            uint4 a1 = ldA(h1i + (size_t)((kk * 4 + rt0 + 1) * 64 + l) * 2);
            #pragma unroll
            for (int ct = 0; ct < 4; ++ct){
              uint4 b = WAu[(((size_t)(cg0 + ct)) * 40 + kk + 8) * 64 + l];
              acc[0][ct] = mfma16(as_s8(a0), as_s8(b), acc[0][ct]);
              acc[1][ct] = mfma16(as_s8(a1), as_s8(b), acc[1][ct]);
            }
          }
        }
      }
    } else {
      if (p >= 1){
        // kh=0: A = h1(t) [parity par]; kh=1: A = h2(t-1) [parity par]
        const unsigned long long* hsrc = (const unsigned long long*)
            ((kh ? h2b : h1b) + (size_t)par * 65536);
        #pragma unroll 4
        for (int i = 0; i < 32; ++i){
          uint4 a0 = ldA(hsrc + (size_t)((i * 4 + rt0    ) * 64 + l) * 2);
          uint4 a1 = ldA(hsrc + (size_t)((i * 4 + rt0 + 1) * 64 + l) * 2);
          #pragma unroll
          for (int ct = 0; ct < 4; ++ct){
            uint4 b = WBu[(((size_t)(cg0 + ct)) * 64 + kh * 32 + i) * 64 + l];
            acc[0][ct] = mfma16(as_s8(a0), as_s8(b), acc[0][ct]);
            acc[1][ct] = mfma16(as_s8(a1), as_s8(b), acc[1][ct]);
          }
        }
      }
    }

    // ---- K-half partials -> LDS ----
    #pragma unroll
    for (int rtl = 0; rtl < 2; ++rtl)
      #pragma unroll
      for (int ct = 0; ct < 4; ++ct)
        *(f4v*)&red[lay][kh][rh][ct][rtl][l][0] = acc[rtl][ct];
    __syncthreads();

    // ---- reduce + cell epilogue: wave (lay,kh,rh) -> cts {2kh,2kh+1}, rows 32rh.. ----
    const bool do_epi = (lay == 0) ? (p < 256) : (p >= 1);
    if (do_epi){
      const int t = lay ? (p - 1) : p;
      float* cc = lay ? c2 : c1;
      const unsigned short* hin  = (lay ? h2b : h1b) + (size_t)par * 65536;
      unsigned short*       hout = (lay ? h2b : h1b) + (size_t)(par ^ 1) * 65536;
      #pragma unroll
      for (int ctl = 0; ctl < 2; ++ctl){
        const int ct = 2 * kh + ctl;
        const int ug = 16 * blk + 4 * ct + u;
        const float bv = (lay ? b2v : b1v)[ug + (g << 10)];
        #pragma unroll
        for (int rtl = 0; rtl < 2; ++rtl){
          const int rt = rt0 + rtl;
          f4v z = *(f4v*)&red[lay][0][rh][ct][rtl][l][0];
          z += *(f4v*)&red[lay][1][rh][ct][rtl][l][0];
          #pragma unroll
          for (int q = 0; q < 4; ++q){
            float zb = z[q] + bv;
            float a1 = __shfl_xor(zb, 4);
            float a2 = __shfl_xor(zb, 8);
            float a3 = __shfl_xor(zb, 12);
            float v0 = zb, v1 = a1, v2 = a2, v3 = a3;   // v_j = gate (g ^ j)
            if (g & 1){ float s = v0; v0 = v1; v1 = s; s = v2; v2 = v3; v3 = s; }
            if (g & 2){ float s = v0; v0 = v2; v2 = s; s = v1; v1 = v3; v3 = s; }
            const int row = 16 * rt + ((l >> 4) << 2) + q;
            float cold = cc[row * 1024 + ug];
            float iv = sig_(v0), fv = sig_(v1), gv = tanh_(v2), ov = sig_(v3);
            float cn = fv * cold + iv * gv;
            float hn = ov * tanh_(cn);
            const int fidx = (((ug >> 5) * 4 + (row >> 4)) * 64 + (row & 15)
                              + (((ug >> 3) & 3) << 4)) * 8 + (ug & 7);
            const bool m = (x[row * 256 + t] != 0);
            if (lay == 0){
              if (!m){ cn = cold; hn = b2f(ldH(hin + fidx)); }
              if (g == 0)      stH(hout + fidx, f2b(hn));
              else if (g == 1) cc[row * 1024 + ug] = cn;
            } else {
              float prev = (t > 0)
                  ? b2f(seq[((size_t)row * 256 + (t - 1)) * 1024 + ug]) : 0.f;
              float outv = hn;
              if (!m){ cn = cold; hn = b2f(ldH(hin + fidx)); outv = prev; }
              if (g == 0)      stH(hout + fidx, f2b(hn));
              else if (g == 1) cc[row * 1024 + ug] = cn;
              else if (g == 2) seq[((size_t)row * 256 + t) * 1024 + ug] = f2b(outv);
            }
          }
        }
      }
    }

    // ---- fence-free grid barrier: monotonic counter, no reset ----
    if (p < 256){
      __syncthreads();                 // drains this block's stores (vmcnt 0)
      if (tid == 0){
        __hip_atomic_fetch_add(bar, 1, __ATOMIC_RELAXED, __HIP_MEMORY_SCOPE_AGENT);
        const int target = 64 * (p + 1);
        while (__hip_atomic_load(bar, __ATOMIC_RELAXED, __HIP_MEMORY_SCOPE_AGENT) < target)
          __builtin_amdgcn_s_sleep(1);
      }
      __syncthreads();
    }
  }
}

// ---------------------------------------------------------------------------
// Decoder GEMM + sigmoid (unchanged)
// ---------------------------------------------------------------------------
__global__ __launch_bounds__(256) void k_dec(const unsigned short* __restrict__ A,
                                             const unsigned short* __restrict__ WF,
                                             const float* __restrict__ bias,
                                             void* __restrict__ outp,
                                             int N, int wf32){
  const int nb = N >> 7;
  const int rm = blockIdx.x / nb, cn = blockIdx.x - rm * nb;
  const int w = threadIdx.x >> 6, l = threadIdx.x & 63;
  const int r0 = rm * 128 + (w >> 1) * 64;
  const int c0 = cn * 128 + (w & 1) * 64;
  f4v acc[4][4];
  #pragma unroll
  for (int i = 0; i < 4; ++i)
    #pragma unroll
    for (int j = 0; j < 4; ++j) acc[i][j] = (f4v){0.f, 0.f, 0.f, 0.f};

  const uint4* WFu = (const uint4*)WF;
  #pragma unroll 4
  for (int ks = 0; ks < 32; ++ks){
    uint4 a4[4], b4[4];
    #pragma unroll
    for (int i = 0; i < 4; ++i)
      a4[i] = *(const uint4*)(A + (size_t)(r0 + 16 * i + (l & 15)) * 1024 + ks * 32 + ((l >> 4) << 3));
    #pragma unroll
    for (int j = 0; j < 4; ++j)
      b4[j] = WFu[(((c0 >> 4) + j) * 32 + ks) * 64 + l];
    #pragma unroll
    for (int i = 0; i < 4; ++i)
      #pragma unroll
      for (int j = 0; j < 4; ++j)
        acc[i][j] = mfma16(as_s8(a4[i]), as_s8(b4[j]), acc[i][j]);
  }
  #pragma unroll
  for (int j = 0; j < 4; ++j){
    const int col = c0 + 16 * j + (l & 15);
    const float bv = bias[col];
    #pragma unroll
    for (int i = 0; i < 4; ++i){
      #pragma unroll
      for (int q = 0; q < 4; ++q){
        const int row = r0 + 16 * i + ((l >> 4) << 2) + q;
        float v = sig_(acc[i][j][q] + bv);
        if (wf32) ((float*)outp)[(size_t)row * N + col] = v;
        else      ((unsigned short*)outp)[(size_t)row * N + col] = f2b(v);
      }
    }
  }
}

// ---------------------------------------------------------------------------
extern "C" void kernel_launch(void* const* d_in, const int* in_sizes, int n_in,
                              void* d_out, int out_size, void* d_ws, size_t ws_size,
                              hipStream_t stream){
  const int*   x    = (const int*)  d_in[0];
  const float* emb  = (const float*)d_in[1];
  const float* W1   = (const float*)d_in[2];
  const float* U1   = (const float*)d_in[3];
  const float* b1   = (const float*)d_in[4];
  const float* W2   = (const float*)d_in[5];
  const float* U2   = (const float*)d_in[6];
  const float* b2   = (const float*)d_in[7];
  const float* Wd1  = (const float*)d_in[8];
  const float* bd1  = (const float*)d_in[9];
  const float* Wd2  = (const float*)d_in[10];
  const float* bd2  = (const float*)d_in[11];

  char* ws = (char*)d_ws;
  unsigned short* WA   = (unsigned short*)(ws + 0);          // 10,485,760
  unsigned short* WB   = (unsigned short*)(ws + 10485760);   // 16,777,216
  unsigned short* Wd1F = (unsigned short*)(ws + 27262976);   //  2,097,152
  unsigned short* Wd2F = (unsigned short*)(ws + 29360128);   //  4,194,304
  unsigned short* esw  = (unsigned short*)(ws + 33554432);   //  8,388,608
  unsigned short* h1b  = (unsigned short*)(ws + 41943040);   //    262,144
  unsigned short* h2b  = (unsigned short*)(ws + 42205184);   //    262,144
  float*          c1   = (float*)        (ws + 42467328);    //    262,144
  float*          c2   = (float*)        (ws + 42729472);    //    262,144
  unsigned short* seq  = (unsigned short*)(ws + 42991616);   // 33,554,432
  unsigned short* hd   = (unsigned short*)(ws + 76546048);   // 33,554,432
  int*            bar  = (int*)          (ws + 110100480);   //      4,096
  (void)in_sizes; (void)n_in; (void)out_size; (void)ws_size;

  // ---- setup ----
  k_pack_AB<<<2560, 256, 0, stream>>>(W1, U1, WA, 40, 256);
  k_pack_AB<<<4096, 256, 0, stream>>>(W2, U2, WB, 64, 1024);
  k_pack_D <<<512,  256, 0, stream>>>(Wd1, Wd1F, 64, 1024);
  k_pack_D <<<1024, 256, 0, stream>>>(Wd2, Wd2F, 128, 2048);
  k_embed  <<<2048, 256, 0, stream>>>(x, emb, esw);
  hipMemsetAsync(ws + 41943040, 0, 1048576, stream);  // h1b, h2b, c1, c2
  hipMemsetAsync(ws + 110100480, 0, 4096, stream);    // barrier counter

  // ---- fence-free persistent scan: 257 phases, 1 dispatch ----
  k_scan<<<64, 512, 0, stream>>>(esw, WA, WB, b1, b2, x,
                                 h1b, h2b, c1, c2, seq, bar);

  // ---- decoder ----
  k_dec<<<1024, 256, 0, stream>>>(seq, Wd1F, bd1, hd,    1024, 0);
  k_dec<<<2048, 256, 0, stream>>>(hd,  Wd2F, bd2, d_out, 2048, 1);
}

// Round 6
// 4212.575 us; speedup vs baseline: 2.1278x; 2.1278x over previous
//
#include <hip/hip_runtime.h>
#include <hip/hip_bf16.h>

// ============================================================================
// Stacked-LSTM LM on MI355X — round 5 kernel (resubmit; round lost to GPU
// acquisition timeout — never compiled/run).
//   Round-4 autopsy: weights serviced from L2 thrashed (6.6MB/XCD demand vs
//   4MB capacity -> 4.25MB/phase HBM refetch) + sc h-loads only ~4 deep.
//   Fix: 256 blocks (1/CU), weights in 128KB LDS (never touch L2 again),
//   blocks 0..127 = layer1 (8 units), 128..255 = layer2 (8 units).
//   Per phase: wave (kh,rt) batch-loads ALL its A-frags (sc, 20-32 in flight)
//   -> MFMA vs LDS B -> K-half partials via block-private global scratch
//   (reuses hd region) -> cell epilogue. Two-level monotonic barrier.
// ws: WA|WB|Wd1F|Wd2F|esw|h1b[2]|h2b[2]|c1|c2|seq|hd(zpart)|bar (~105 MB)
// ============================================================================

#define DI __device__ __forceinline__

typedef __attribute__((ext_vector_type(8))) short s8v;   // 8 x bf16 bits
typedef __attribute__((ext_vector_type(4))) float f4v;   // MFMA accumulator

DI f4v mfma16(s8v a, s8v b, f4v c){
  return __builtin_amdgcn_mfma_f32_16x16x32_bf16(a, b, c, 0, 0, 0);
}
DI s8v as_s8(uint4 u){ return __builtin_bit_cast(s8v, u); }

DI unsigned short f2b(float f){            // fp32 -> bf16 bits, RNE
  unsigned u = __float_as_uint(f);
  u = u + 0x7fffu + ((u >> 16) & 1u);
  return (unsigned short)(u >> 16);
}
DI float b2f(unsigned short h){ return __uint_as_float(((unsigned)h) << 16); }
DI float sig_(float x){ return 1.f / (1.f + __expf(-x)); }
DI float tanh_(float x){ return 1.f - 2.f / (__expf(2.f * x) + 1.f); }

// Coherent (agent-scope, L2-bypass) ops for cross-block h-state.
DI uint4 ldA(const unsigned long long* p){
  unsigned long long lo = __hip_atomic_load(p,     __ATOMIC_RELAXED, __HIP_MEMORY_SCOPE_AGENT);
  unsigned long long hi = __hip_atomic_load(p + 1, __ATOMIC_RELAXED, __HIP_MEMORY_SCOPE_AGENT);
  uint4 r; r.x = (unsigned)lo; r.y = (unsigned)(lo >> 32);
  r.z = (unsigned)hi; r.w = (unsigned)(hi >> 32);
  return r;
}
DI unsigned short ldH(const unsigned short* p){
  return __hip_atomic_load(p, __ATOMIC_RELAXED, __HIP_MEMORY_SCOPE_AGENT);
}
DI void stH(unsigned short* p, unsigned short v){
  __hip_atomic_store(p, v, __ATOMIC_RELAXED, __HIP_MEMORY_SCOPE_AGENT);
}

// ---------------------------------------------------------------------------
// Setup kernels (unchanged)
// ---------------------------------------------------------------------------
__global__ __launch_bounds__(256) void k_pack_AB(const float* __restrict__ Wx,
                                                 const float* __restrict__ Ux,
                                                 unsigned short* __restrict__ dst,
                                                 int KS, int kx){
  int idx = blockIdx.x * 256 + threadIdx.x;
  if (idx >= 256 * KS * 64) return;
  int l = idx & 63, rest = idx >> 6;
  int ks = rest % KS, b = rest / KS;
  int c = l & 15;
  int col = 4 * b + (c & 3) + ((c >> 2) << 10);
  int k0 = ks * 32 + ((l >> 4) << 3);
  const float* src = (k0 < kx) ? (Wx + (size_t)k0 * 4096)
                               : (Ux + (size_t)(k0 - kx) * 4096);
  unsigned v[4];
  #pragma unroll
  for (int p = 0; p < 4; ++p){
    unsigned short lo = f2b(src[(size_t)(2 * p) * 4096 + col]);
    unsigned short hi = f2b(src[(size_t)(2 * p + 1) * 4096 + col]);
    v[p] = (unsigned)lo | ((unsigned)hi << 16);
  }
  uint4 o; o.x = v[0]; o.y = v[1]; o.z = v[2]; o.w = v[3];
  ((uint4*)dst)[idx] = o;
}

__global__ __launch_bounds__(256) void k_pack_D(const float* __restrict__ W,
                                                unsigned short* __restrict__ dst,
                                                int CG, int N){
  int idx = blockIdx.x * 256 + threadIdx.x;
  if (idx >= CG * 32 * 64) return;
  int l = idx & 63;
  int ks = (idx >> 6) & 31;
  int cg = idx >> 11;
  int col = 16 * cg + (l & 15);
  int k0 = 32 * ks + ((l >> 4) << 3);
  unsigned v[4];
  #pragma unroll
  for (int p = 0; p < 4; ++p){
    unsigned short lo = f2b(W[(size_t)(k0 + 2 * p) * N + col]);
    unsigned short hi = f2b(W[(size_t)(k0 + 2 * p + 1) * N + col]);
    v[p] = (unsigned)lo | ((unsigned)hi << 16);
  }
  uint4 o; o.x = v[0]; o.y = v[1]; o.z = v[2]; o.w = v[3];
  ((uint4*)dst)[idx] = o;
}

__global__ __launch_bounds__(256) void k_embed(const int* __restrict__ x,
                                               const float* __restrict__ emb,
                                               unsigned short* __restrict__ dst){
  int idx = blockIdx.x * 256 + threadIdx.x;
  int l = idx & 63;
  int w = (idx >> 6) & 3;
  int ks = (idx >> 8) & 7;
  int t = idx >> 11;
  int row = 16 * w + (l & 15);
  int xi = x[row * 256 + t];
  int k0 = 32 * ks + ((l >> 4) << 3);
  const float* src = emb + (size_t)xi * 256 + k0;
  unsigned v[4];
  #pragma unroll
  for (int p = 0; p < 4; ++p){
    unsigned short lo = f2b(src[2 * p]);
    unsigned short hi = f2b(src[2 * p + 1]);
    v[p] = (unsigned)lo | ((unsigned)hi << 16);
  }
  uint4 o; o.x = v[0]; o.y = v[1]; o.z = v[2]; o.w = v[3];
  ((uint4*)dst)[idx] = o;
}

// ---------------------------------------------------------------------------
// Persistent scan: 256 blocks x 512 threads (8 waves), 1 block/CU (128KB LDS).
//   blk <  128: LAYER-1 block bk=blk,   owns units 8bk..8bk+7 (col-grp 2bk,2bk+1)
//   blk >= 128: LAYER-2 block bk=blk-128, same unit ownership for layer 2.
// Wave w: kh = w>>2 (K half), rt = w&3 (16-row tile).
// Phase p: L1 computes step t=p (p<256); L2 computes t=p-1 (p>=1).
// K-half partials cross waves via block-private global zpart (hd region).
// ---------------------------------------------------------------------------
__global__ __launch_bounds__(512, 2) void k_scan(
    const unsigned short* __restrict__ esw,
    const unsigned short* __restrict__ WA,
    const unsigned short* __restrict__ WB,
    const float* __restrict__ b1v, const float* __restrict__ b2v,
    const int* __restrict__ x,
    unsigned short* __restrict__ h1b, unsigned short* __restrict__ h2b,
    float* __restrict__ c1, float* __restrict__ c2,
    unsigned short* __restrict__ seq, float* __restrict__ zpart,
    int* __restrict__ bar){
  __shared__ uint4 Blds[2][64][64];            // 128 KB: [ct][kk][lane]
  const int blk = blockIdx.x, tid = threadIdx.x;
  const int w = tid >> 6, l = tid & 63;
  const bool isL2 = (blk >= 128);
  const int bk = isL2 ? blk - 128 : blk;
  const int kh = w >> 2, rt = w & 3;
  const int c = l & 15, u = c & 3, g = c >> 2;
  const uint4* WAu  = (const uint4*)WA;
  const uint4* WBu  = (const uint4*)WB;
  const uint4* eswU = (const uint4*)esw;

  // ---- one-time: weight slice -> LDS ----
  if (!isL2){
    for (int i = tid; i < 5120; i += 512){      // 2 ct x 40 kk x 64 l
      int ct = (i >= 2560) ? 1 : 0;
      int r = ct ? i - 2560 : i;
      Blds[ct][r >> 6][r & 63] = WAu[((size_t)(2 * bk + ct) * 40 + (r >> 6)) * 64 + (r & 63)];
    }
  } else {
    for (int i = tid; i < 8192; i += 512){      // 2 ct x 64 kk x 64 l
      int ct = i >> 12;
      int r = i & 4095;
      Blds[ct][r >> 6][r & 63] = WBu[((size_t)(2 * bk + ct) * 64 + (r >> 6)) * 64 + (r & 63)];
    }
  }
  __syncthreads();

  #pragma unroll 1
  for (int p = 0; p <= 256; ++p){
    const int par = p & 1;
    const bool active = isL2 ? (p >= 1) : (p < 256);
    f4v acc0 = {0.f, 0.f, 0.f, 0.f};
    f4v acc1 = {0.f, 0.f, 0.f, 0.f};

    if (!isL2){
      if (active){
        const unsigned long long* h1p =
            (const unsigned long long*)(h1b + (size_t)par * 65536);
        if (kh == 0){
          uint4 a[20];
          const uint4* eswT = eswU + (size_t)p * 2048;
          #pragma unroll
          for (int j = 0; j < 8; ++j)
            a[j] = eswT[(j * 4 + rt) * 64 + l];
          #pragma unroll
          for (int j = 0; j < 12; ++j)
            a[8 + j] = ldA(h1p + (size_t)((j * 4 + rt) * 64 + l) * 2);
          #pragma unroll
          for (int j = 0; j < 20; ++j){
            acc0 = mfma16(as_s8(a[j]), as_s8(Blds[0][j][l]), acc0);
            acc1 = mfma16(as_s8(a[j]), as_s8(Blds[1][j][l]), acc1);
          }
        } else {
          uint4 a[20];
          #pragma unroll
          for (int j = 0; j < 20; ++j)
            a[j] = ldA(h1p + (size_t)(((j + 12) * 4 + rt) * 64 + l) * 2);
          #pragma unroll
          for (int j = 0; j < 20; ++j){
            acc0 = mfma16(as_s8(a[j]), as_s8(Blds[0][20 + j][l]), acc0);
            acc1 = mfma16(as_s8(a[j]), as_s8(Blds[1][20 + j][l]), acc1);
          }
        }
      }
    } else {
      if (active){
        // kh=0: A = h1(t=p-1); kh=1: A = h2(t=p-2). Both at parity `par`.
        const unsigned long long* hp = (const unsigned long long*)
            ((kh ? h2b : h1b) + (size_t)par * 65536);
        uint4 a[32];
        #pragma unroll
        for (int j = 0; j < 32; ++j)
          a[j] = ldA(hp + (size_t)((j * 4 + rt) * 64 + l) * 2);
        const int kb = kh * 32;
        #pragma unroll
        for (int j = 0; j < 32; ++j){
          acc0 = mfma16(as_s8(a[j]), as_s8(Blds[0][kb + j][l]), acc0);
          acc1 = mfma16(as_s8(a[j]), as_s8(Blds[1][kb + j][l]), acc1);
        }
      }
    }

    // ---- K-half reduction via block-private global scratch ----
    f4v* zp = (f4v*)zpart;
    const size_t zbase = ((size_t)blk * 4 + rt) * 2;
    if (kh == 1){
      zp[(zbase + 0) * 64 + l] = acc0;
      zp[(zbase + 1) * 64 + l] = acc1;
    }
    __syncthreads();

    if (kh == 0 && active){
      acc0 += zp[(zbase + 0) * 64 + l];
      acc1 += zp[(zbase + 1) * 64 + l];

      const int t = isL2 ? (p - 1) : p;
      float* cc = isL2 ? c2 : c1;
      const float* bb = isL2 ? b2v : b1v;
      const unsigned short* hin  = (isL2 ? h2b : h1b) + (size_t)par * 65536;
      unsigned short*       hout = (isL2 ? h2b : h1b) + (size_t)(par ^ 1) * 65536;

      #pragma unroll
      for (int ct = 0; ct < 2; ++ct){
        f4v z = ct ? acc1 : acc0;
        const int ug = 8 * bk + 4 * ct + u;
        const float bv = bb[ug + (g << 10)];
        #pragma unroll
        for (int q = 0; q < 4; ++q){
          float zb = z[q] + bv;
          float a1 = __shfl_xor(zb, 4);
          float a2 = __shfl_xor(zb, 8);
          float a3 = __shfl_xor(zb, 12);
          float v0 = zb, v1 = a1, v2 = a2, v3 = a3;   // v_j = gate (g ^ j)
          if (g & 1){ float s = v0; v0 = v1; v1 = s; s = v2; v2 = v3; v3 = s; }
          if (g & 2){ float s = v0; v0 = v2; v2 = s; s = v1; v1 = v3; v3 = s; }
          const int row = 16 * rt + ((l >> 4) << 2) + q;
          float cold = cc[row * 1024 + ug];
          float iv = sig_(v0), fv = sig_(v1), gv = tanh_(v2), ov = sig_(v3);
          float cn = fv * cold + iv * gv;
          float hn = ov * tanh_(cn);
          const int fidx = (((ug >> 5) * 4 + (row >> 4)) * 64 + (row & 15)
                            + (((ug >> 3) & 3) << 4)) * 8 + (ug & 7);
          const bool m = (x[row * 256 + t] != 0);
          if (!isL2){
            if (!m){ cn = cold; hn = b2f(ldH(hin + fidx)); }
            if (g == 0)      stH(hout + fidx, f2b(hn));
            else if (g == 1) cc[row * 1024 + ug] = cn;
          } else {
            float prev = (t > 0)
                ? b2f(seq[((size_t)row * 256 + (t - 1)) * 1024 + ug]) : 0.f;
            float outv = hn;
            if (!m){ cn = cold; hn = b2f(ldH(hin + fidx)); outv = prev; }
            if (g == 0)      stH(hout + fidx, f2b(hn));
            else if (g == 1) cc[row * 1024 + ug] = cn;
            else if (g == 2) seq[((size_t)row * 256 + t) * 1024 + ug] = f2b(outv);
          }
        }
      }
    }

    // ---- two-level monotonic grid barrier (8 groups x 32 blocks) ----
    if (p < 256){
      __syncthreads();                 // drains all waves' stores (vmcnt 0)
      if (tid == 0){
        int v = __hip_atomic_fetch_add(bar + (blk >> 5) * 64, 1,
                                       __ATOMIC_RELAXED, __HIP_MEMORY_SCOPE_AGENT);
        if (v == 32 * (p + 1) - 1)
          __hip_atomic_fetch_add(bar + 512, 1,
                                 __ATOMIC_RELAXED, __HIP_MEMORY_SCOPE_AGENT);
        const int target = 8 * (p + 1);
        while (__hip_atomic_load(bar + 512, __ATOMIC_RELAXED,
                                 __HIP_MEMORY_SCOPE_AGENT) < target)
          __builtin_amdgcn_s_sleep(2);
      }
      __syncthreads();
    }
  }
}

// ---------------------------------------------------------------------------
// Decoder GEMM + sigmoid (unchanged)
// ---------------------------------------------------------------------------
__global__ __launch_bounds__(256) void k_dec(const unsigned short* __restrict__ A,
                                             const unsigned short* __restrict__ WF,
                                             const float* __restrict__ bias,
                                             void* __restrict__ outp,
                                             int N, int wf32){
  const int nb = N >> 7;
  const int rm = blockIdx.x / nb, cn = blockIdx.x - rm * nb;
  const int w = threadIdx.x >> 6, l = threadIdx.x & 63;
  const int r0 = rm * 128 + (w >> 1) * 64;
  const int c0 = cn * 128 + (w & 1) * 64;
  f4v acc[4][4];
  #pragma unroll
  for (int i = 0; i < 4; ++i)
    #pragma unroll
    for (int j = 0; j < 4; ++j) acc[i][j] = (f4v){0.f, 0.f, 0.f, 0.f};

  const uint4* WFu = (const uint4*)WF;
  #pragma unroll 4
  for (int ks = 0; ks < 32; ++ks){
    uint4 a4[4], b4[4];
    #pragma unroll
    for (int i = 0; i < 4; ++i)
      a4[i] = *(const uint4*)(A + (size_t)(r0 + 16 * i + (l & 15)) * 1024 + ks * 32 + ((l >> 4) << 3));
    #pragma unroll
    for (int j = 0; j < 4; ++j)
      b4[j] = WFu[(((c0 >> 4) + j) * 32 + ks) * 64 + l];
    #pragma unroll
    for (int i = 0; i < 4; ++i)
      #pragma unroll
      for (int j = 0; j < 4; ++j)
        acc[i][j] = mfma16(as_s8(a4[i]), as_s8(b4[j]), acc[i][j]);
  }
  #pragma unroll
  for (int j = 0; j < 4; ++j){
    const int col = c0 + 16 * j + (l & 15);
    const float bv = bias[col];
    #pragma unroll
    for (int i = 0; i < 4; ++i){
      #pragma unroll
      for (int q = 0; q < 4; ++q){
        const int row = r0 + 16 * i + ((l >> 4) << 2) + q;
        float v = sig_(acc[i][j][q] + bv);
        if (wf32) ((float*)outp)[(size_t)row * N + col] = v;
        else      ((unsigned short*)outp)[(size_t)row * N + col] = f2b(v);
      }
    }
  }
}

// ---------------------------------------------------------------------------
extern "C" void kernel_launch(void* const* d_in, const int* in_sizes, int n_in,
                              void* d_out, int out_size, void* d_ws, size_t ws_size,
                              hipStream_t stream){
  const int*   x    = (const int*)  d_in[0];
  const float* emb  = (const float*)d_in[1];
  const float* W1   = (const float*)d_in[2];
  const float* U1   = (const float*)d_in[3];
  const float* b1   = (const float*)d_in[4];
  const float* W2   = (const float*)d_in[5];
  const float* U2   = (const float*)d_in[6];
  const float* b2   = (const float*)d_in[7];
  const float* Wd1  = (const float*)d_in[8];
  const float* bd1  = (const float*)d_in[9];
  const float* Wd2  = (const float*)d_in[10];
  const float* bd2  = (const float*)d_in[11];

  char* ws = (char*)d_ws;
  unsigned short* WA   = (unsigned short*)(ws + 0);          // 10,485,760
  unsigned short* WB   = (unsigned short*)(ws + 10485760);   // 16,777,216
  unsigned short* Wd1F = (unsigned short*)(ws + 27262976);   //  2,097,152
  unsigned short* Wd2F = (unsigned short*)(ws + 29360128);   //  4,194,304
  unsigned short* esw  = (unsigned short*)(ws + 33554432);   //  8,388,608
  unsigned short* h1b  = (unsigned short*)(ws + 41943040);   //    262,144
  unsigned short* h2b  = (unsigned short*)(ws + 42205184);   //    262,144
  float*          c1   = (float*)        (ws + 42467328);    //    262,144
  float*          c2   = (float*)        (ws + 42729472);    //    262,144
  unsigned short* seq  = (unsigned short*)(ws + 42991616);   // 33,554,432
  unsigned short* hd   = (unsigned short*)(ws + 76546048);   // 33,554,432 (zpart reuses head during scan)
  int*            bar  = (int*)          (ws + 110100480);   //      4,096
  float*          zpart = (float*)hd;                        //  2 MB scratch, scan-only
  (void)in_sizes; (void)n_in; (void)out_size; (void)ws_size;

  // ---- setup ----
  k_pack_AB<<<2560, 256, 0, stream>>>(W1, U1, WA, 40, 256);
  k_pack_AB<<<4096, 256, 0, stream>>>(W2, U2, WB, 64, 1024);
  k_pack_D <<<512,  256, 0, stream>>>(Wd1, Wd1F, 64, 1024);
  k_pack_D <<<1024, 256, 0, stream>>>(Wd2, Wd2F, 128, 2048);
  k_embed  <<<2048, 256, 0, stream>>>(x, emb, esw);
  hipMemsetAsync(ws + 41943040, 0, 1048576, stream);  // h1b, h2b, c1, c2
  hipMemsetAsync(ws + 110100480, 0, 4096, stream);    // barrier counters

  // ---- persistent scan: 257 phases, 1 dispatch, 256 CUs ----
  k_scan<<<256, 512, 0, stream>>>(esw, WA, WB, b1, b2, x,
                                  h1b, h2b, c1, c2, seq, zpart, bar);

  // ---- decoder ----
  k_dec<<<1024, 256, 0, stream>>>(seq, Wd1F, bd1, hd,    1024, 0);
  k_dec<<<2048, 256, 0, stream>>>(hd,  Wd2F, bd2, d_out, 2048, 1);
}

// Round 7
// 3919.426 us; speedup vs baseline: 2.2870x; 1.0748x over previous
//
#include <hip/hip_runtime.h>
#include <hip/hip_bf16.h>

// ============================================================================
// Stacked-LSTM LM on MI355X — round 7: write-once h-rings -> L2-cached broadcast.
//   Round-6 autopsy: phase = 14.9 µs, of which ~12 µs = h broadcast via
//   agent-scope atomic loads (48 MB/phase all served at the L3 coherence
//   point, 0% L2-cacheable) + barrier. MFMA busy only 0.7 µs/phase.
//   Fix: h state in 32-slot write-once rings (inside scan-idle hd region).
//   Writers keep sc stores (write-through -> L3 fresh). Readers use PLAIN
//   cached loads: slot address untouched for 31 phases -> no stale L2/L1
//   lines; first toucher per XCD fills from L3, rest hit local L2.
//   Fabric traffic 48 MB -> 2 MB/phase; per-CU reads now local-L2 speed.
//   Everything else identical to round 6 (LDS weights, zpart, barrier).
// ws: WA|WB|Wd1F|Wd2F|esw|(old h/c area: c1,c2)|seq|hd{zpart,h1ring,h2ring}|bar
// ============================================================================

#define DI __device__ __forceinline__

typedef __attribute__((ext_vector_type(8))) short s8v;   // 8 x bf16 bits
typedef __attribute__((ext_vector_type(4))) float f4v;   // MFMA accumulator

DI f4v mfma16(s8v a, s8v b, f4v c){
  return __builtin_amdgcn_mfma_f32_16x16x32_bf16(a, b, c, 0, 0, 0);
}
DI s8v as_s8(uint4 u){ return __builtin_bit_cast(s8v, u); }

DI unsigned short f2b(float f){            // fp32 -> bf16 bits, RNE
  unsigned u = __float_as_uint(f);
  u = u + 0x7fffu + ((u >> 16) & 1u);
  return (unsigned short)(u >> 16);
}
DI float b2f(unsigned short h){ return __uint_as_float(((unsigned)h) << 16); }
DI float sig_(float x){ return 1.f / (1.f + __expf(-x)); }
DI float tanh_(float x){ return 1.f - 2.f / (__expf(2.f * x) + 1.f); }

// Coherent (agent-scope) store for h-state: write-through to the L3
// coherence point so remote XCDs' L2-miss fills see fresh data.
DI void stH(unsigned short* p, unsigned short v){
  __hip_atomic_store(p, v, __ATOMIC_RELAXED, __HIP_MEMORY_SCOPE_AGENT);
}

// ---------------------------------------------------------------------------
// Setup kernels (unchanged)
// ---------------------------------------------------------------------------
__global__ __launch_bounds__(256) void k_pack_AB(const float* __restrict__ Wx,
                                                 const float* __restrict__ Ux,
                                                 unsigned short* __restrict__ dst,
                                                 int KS, int kx){
  int idx = blockIdx.x * 256 + threadIdx.x;
  if (idx >= 256 * KS * 64) return;
  int l = idx & 63, rest = idx >> 6;
  int ks = rest % KS, b = rest / KS;
  int c = l & 15;
  int col = 4 * b + (c & 3) + ((c >> 2) << 10);
  int k0 = ks * 32 + ((l >> 4) << 3);
  const float* src = (k0 < kx) ? (Wx + (size_t)k0 * 4096)
                               : (Ux + (size_t)(k0 - kx) * 4096);
  unsigned v[4];
  #pragma unroll
  for (int p = 0; p < 4; ++p){
    unsigned short lo = f2b(src[(size_t)(2 * p) * 4096 + col]);
    unsigned short hi = f2b(src[(size_t)(2 * p + 1) * 4096 + col]);
    v[p] = (unsigned)lo | ((unsigned)hi << 16);
  }
  uint4 o; o.x = v[0]; o.y = v[1]; o.z = v[2]; o.w = v[3];
  ((uint4*)dst)[idx] = o;
}

__global__ __launch_bounds__(256) void k_pack_D(const float* __restrict__ W,
                                                unsigned short* __restrict__ dst,
                                                int CG, int N){
  int idx = blockIdx.x * 256 + threadIdx.x;
  if (idx >= CG * 32 * 64) return;
  int l = idx & 63;
  int ks = (idx >> 6) & 31;
  int cg = idx >> 11;
  int col = 16 * cg + (l & 15);
  int k0 = 32 * ks + ((l >> 4) << 3);
  unsigned v[4];
  #pragma unroll
  for (int p = 0; p < 4; ++p){
    unsigned short lo = f2b(W[(size_t)(k0 + 2 * p) * N + col]);
    unsigned short hi = f2b(W[(size_t)(k0 + 2 * p + 1) * N + col]);
    v[p] = (unsigned)lo | ((unsigned)hi << 16);
  }
  uint4 o; o.x = v[0]; o.y = v[1]; o.z = v[2]; o.w = v[3];
  ((uint4*)dst)[idx] = o;
}

__global__ __launch_bounds__(256) void k_embed(const int* __restrict__ x,
                                               const float* __restrict__ emb,
                                               unsigned short* __restrict__ dst){
  int idx = blockIdx.x * 256 + threadIdx.x;
  int l = idx & 63;
  int w = (idx >> 6) & 3;
  int ks = (idx >> 8) & 7;
  int t = idx >> 11;
  int row = 16 * w + (l & 15);
  int xi = x[row * 256 + t];
  int k0 = 32 * ks + ((l >> 4) << 3);
  const float* src = emb + (size_t)xi * 256 + k0;
  unsigned v[4];
  #pragma unroll
  for (int p = 0; p < 4; ++p){
    unsigned short lo = f2b(src[2 * p]);
    unsigned short hi = f2b(src[2 * p + 1]);
    v[p] = (unsigned)lo | ((unsigned)hi << 16);
  }
  uint4 o; o.x = v[0]; o.y = v[1]; o.z = v[2]; o.w = v[3];
  ((uint4*)dst)[idx] = o;
}

// ---------------------------------------------------------------------------
// Persistent scan: 256 blocks x 512 threads (8 waves), 1 block/CU (128KB LDS).
//   blk <  128: LAYER-1 block bk=blk,   owns units 8bk..8bk+7
//   blk >= 128: LAYER-2 block bk=blk-128, same unit ownership for layer 2.
// Wave w: kh = w>>2 (K half), rt = w&3 (16-row tile).
// Phase p: L1 computes step t=p (p<256); L2 computes t=p-1 (p>=1).
// h rings: 32 slots x 128KB; phase p reads slot p&31, writes slot (p+1)&31.
// ---------------------------------------------------------------------------
__global__ __launch_bounds__(512, 2) void k_scan(
    const unsigned short* __restrict__ esw,
    const unsigned short* __restrict__ WA,
    const unsigned short* __restrict__ WB,
    const float* __restrict__ b1v, const float* __restrict__ b2v,
    const int* __restrict__ x,
    unsigned short* __restrict__ h1r, unsigned short* __restrict__ h2r,
    float* __restrict__ c1, float* __restrict__ c2,
    unsigned short* __restrict__ seq, float* __restrict__ zpart,
    int* __restrict__ bar){
  __shared__ uint4 Blds[2][64][64];            // 128 KB: [ct][kk][lane]
  const int blk = blockIdx.x, tid = threadIdx.x;
  const int w = tid >> 6, l = tid & 63;
  const bool isL2 = (blk >= 128);
  const int bk = isL2 ? blk - 128 : blk;
  const int kh = w >> 2, rt = w & 3;
  const int c = l & 15, u = c & 3, g = c >> 2;
  const uint4* WAu  = (const uint4*)WA;
  const uint4* WBu  = (const uint4*)WB;
  const uint4* eswU = (const uint4*)esw;

  // ---- one-time: weight slice -> LDS ----
  if (!isL2){
    for (int i = tid; i < 5120; i += 512){      // 2 ct x 40 kk x 64 l
      int ct = (i >= 2560) ? 1 : 0;
      int r = ct ? i - 2560 : i;
      Blds[ct][r >> 6][r & 63] = WAu[((size_t)(2 * bk + ct) * 40 + (r >> 6)) * 64 + (r & 63)];
    }
  } else {
    for (int i = tid; i < 8192; i += 512){      // 2 ct x 64 kk x 64 l
      int ct = i >> 12;
      int r = i & 4095;
      Blds[ct][r >> 6][r & 63] = WBu[((size_t)(2 * bk + ct) * 64 + (r >> 6)) * 64 + (r & 63)];
    }
  }
  __syncthreads();

  #pragma unroll 1
  for (int p = 0; p <= 256; ++p){
    const bool active = isL2 ? (p >= 1) : (p < 256);
    // ring slots: read slot p&31 (written at phase p-1), write slot (p+1)&31
    const uint4* h1i = (const uint4*)(h1r + (size_t)(p & 31) * 65536);
    const uint4* h2i = (const uint4*)(h2r + (size_t)(p & 31) * 65536);
    f4v acc0 = {0.f, 0.f, 0.f, 0.f};
    f4v acc1 = {0.f, 0.f, 0.f, 0.f};

    if (!isL2){
      if (active){
        if (kh == 0){
          uint4 a[20];
          const uint4* eswT = eswU + (size_t)p * 2048;
          #pragma unroll
          for (int j = 0; j < 8; ++j)
            a[j] = eswT[(j * 4 + rt) * 64 + l];
          #pragma unroll
          for (int j = 0; j < 12; ++j)
            a[8 + j] = h1i[(j * 4 + rt) * 64 + l];
          #pragma unroll
          for (int j = 0; j < 20; ++j){
            acc0 = mfma16(as_s8(a[j]), as_s8(Blds[0][j][l]), acc0);
            acc1 = mfma16(as_s8(a[j]), as_s8(Blds[1][j][l]), acc1);
          }
        } else {
          uint4 a[20];
          #pragma unroll
          for (int j = 0; j < 20; ++j)
            a[j] = h1i[((j + 12) * 4 + rt) * 64 + l];
          #pragma unroll
          for (int j = 0; j < 20; ++j){
            acc0 = mfma16(as_s8(a[j]), as_s8(Blds[0][20 + j][l]), acc0);
            acc1 = mfma16(as_s8(a[j]), as_s8(Blds[1][20 + j][l]), acc1);
          }
        }
      }
    } else {
      if (active){
        // kh=0: A = h1(t=p-1); kh=1: A = h2(t=p-2). Both in slot p&31.
        const uint4* hp = kh ? h2i : h1i;
        uint4 a[32];
        #pragma unroll
        for (int j = 0; j < 32; ++j)
          a[j] = hp[(j * 4 + rt) * 64 + l];
        const int kb = kh * 32;
        #pragma unroll
        for (int j = 0; j < 32; ++j){
          acc0 = mfma16(as_s8(a[j]), as_s8(Blds[0][kb + j][l]), acc0);
          acc1 = mfma16(as_s8(a[j]), as_s8(Blds[1][kb + j][l]), acc1);
        }
      }
    }

    // ---- K-half reduction via block-private global scratch ----
    f4v* zp = (f4v*)zpart;
    const size_t zbase = ((size_t)blk * 4 + rt) * 2;
    if (kh == 1){
      zp[(zbase + 0) * 64 + l] = acc0;
      zp[(zbase + 1) * 64 + l] = acc1;
    }
    __syncthreads();

    if (kh == 0 && active){
      acc0 += zp[(zbase + 0) * 64 + l];
      acc1 += zp[(zbase + 1) * 64 + l];

      const int t = isL2 ? (p - 1) : p;
      float* cc = isL2 ? c2 : c1;
      const float* bb = isL2 ? b2v : b1v;
      const unsigned short* hin  = (isL2 ? h2r : h1r) + (size_t)(p & 31) * 65536;
      unsigned short*       hout = (isL2 ? h2r : h1r) + (size_t)((p + 1) & 31) * 65536;

      #pragma unroll
      for (int ct = 0; ct < 2; ++ct){
        f4v z = ct ? acc1 : acc0;
        const int ug = 8 * bk + 4 * ct + u;
        const float bv = bb[ug + (g << 10)];
        #pragma unroll
        for (int q = 0; q < 4; ++q){
          float zb = z[q] + bv;
          float a1 = __shfl_xor(zb, 4);
          float a2 = __shfl_xor(zb, 8);
          float a3 = __shfl_xor(zb, 12);
          float v0 = zb, v1 = a1, v2 = a2, v3 = a3;   // v_j = gate (g ^ j)
          if (g & 1){ float s = v0; v0 = v1; v1 = s; s = v2; v2 = v3; v3 = s; }
          if (g & 2){ float s = v0; v0 = v2; v2 = s; s = v1; v1 = v3; v3 = s; }
          const int row = 16 * rt + ((l >> 4) << 2) + q;
          float cold = cc[row * 1024 + ug];
          float iv = sig_(v0), fv = sig_(v1), gv = tanh_(v2), ov = sig_(v3);
          float cn = fv * cold + iv * gv;
          float hn = ov * tanh_(cn);
          const int fidx = (((ug >> 5) * 4 + (row >> 4)) * 64 + (row & 15)
                            + (((ug >> 3) & 3) << 4)) * 8 + (ug & 7);
          const bool m = (x[row * 256 + t] != 0);
          if (!isL2){
            if (!m){ cn = cold; hn = b2f(hin[fidx]); }
            if (g == 0)      stH(hout + fidx, f2b(hn));
            else if (g == 1) cc[row * 1024 + ug] = cn;
          } else {
            float prev = (t > 0)
                ? b2f(seq[((size_t)row * 256 + (t - 1)) * 1024 + ug]) : 0.f;
            float outv = hn;
            if (!m){ cn = cold; hn = b2f(hin[fidx]); outv = prev; }
            if (g == 0)      stH(hout + fidx, f2b(hn));
            else if (g == 1) cc[row * 1024 + ug] = cn;
            else if (g == 2) seq[((size_t)row * 256 + t) * 1024 + ug] = f2b(outv);
          }
        }
      }
    }

    // ---- two-level monotonic grid barrier (8 groups x 32 blocks) ----
    if (p < 256){
      __syncthreads();                 // drains all waves' stores (vmcnt 0)
      if (tid == 0){
        int v = __hip_atomic_fetch_add(bar + (blk >> 5) * 64, 1,
                                       __ATOMIC_RELAXED, __HIP_MEMORY_SCOPE_AGENT);
        if (v == 32 * (p + 1) - 1)
          __hip_atomic_fetch_add(bar + 512, 1,
                                 __ATOMIC_RELAXED, __HIP_MEMORY_SCOPE_AGENT);
        const int target = 8 * (p + 1);
        while (__hip_atomic_load(bar + 512, __ATOMIC_RELAXED,
                                 __HIP_MEMORY_SCOPE_AGENT) < target)
          __builtin_amdgcn_s_sleep(2);
      }
      __syncthreads();
    }
  }
}

// ---------------------------------------------------------------------------
// Decoder GEMM + sigmoid (unchanged)
// ---------------------------------------------------------------------------
__global__ __launch_bounds__(256) void k_dec(const unsigned short* __restrict__ A,
                                             const unsigned short* __restrict__ WF,
                                             const float* __restrict__ bias,
                                             void* __restrict__ outp,
                                             int N, int wf32){
  const int nb = N >> 7;
  const int rm = blockIdx.x / nb, cn = blockIdx.x - rm * nb;
  const int w = threadIdx.x >> 6, l = threadIdx.x & 63;
  const int r0 = rm * 128 + (w >> 1) * 64;
  const int c0 = cn * 128 + (w & 1) * 64;
  f4v acc[4][4];
  #pragma unroll
  for (int i = 0; i < 4; ++i)
    #pragma unroll
    for (int j = 0; j < 4; ++j) acc[i][j] = (f4v){0.f, 0.f, 0.f, 0.f};

  const uint4* WFu = (const uint4*)WF;
  #pragma unroll 4
  for (int ks = 0; ks < 32; ++ks){
    uint4 a4[4], b4[4];
    #pragma unroll
    for (int i = 0; i < 4; ++i)
      a4[i] = *(const uint4*)(A + (size_t)(r0 + 16 * i + (l & 15)) * 1024 + ks * 32 + ((l >> 4) << 3));
    #pragma unroll
    for (int j = 0; j < 4; ++j)
      b4[j] = WFu[(((c0 >> 4) + j) * 32 + ks) * 64 + l];
    #pragma unroll
    for (int i = 0; i < 4; ++i)
      #pragma unroll
      for (int j = 0; j < 4; ++j)
        acc[i][j] = mfma16(as_s8(a4[i]), as_s8(b4[j]), acc[i][j]);
  }
  #pragma unroll
  for (int j = 0; j < 4; ++j){
    const int col = c0 + 16 * j + (l & 15);
    const float bv = bias[col];
    #pragma unroll
    for (int i = 0; i < 4; ++i){
      #pragma unroll
      for (int q = 0; q < 4; ++q){
        const int row = r0 + 16 * i + ((l >> 4) << 2) + q;
        float v = sig_(acc[i][j][q] + bv);
        if (wf32) ((float*)outp)[(size_t)row * N + col] = v;
        else      ((unsigned short*)outp)[(size_t)row * N + col] = f2b(v);
      }
    }
  }
}

// ---------------------------------------------------------------------------
extern "C" void kernel_launch(void* const* d_in, const int* in_sizes, int n_in,
                              void* d_out, int out_size, void* d_ws, size_t ws_size,
                              hipStream_t stream){
  const int*   x    = (const int*)  d_in[0];
  const float* emb  = (const float*)d_in[1];
  const float* W1   = (const float*)d_in[2];
  const float* U1   = (const float*)d_in[3];
  const float* b1   = (const float*)d_in[4];
  const float* W2   = (const float*)d_in[5];
  const float* U2   = (const float*)d_in[6];
  const float* b2   = (const float*)d_in[7];
  const float* Wd1  = (const float*)d_in[8];
  const float* bd1  = (const float*)d_in[9];
  const float* Wd2  = (const float*)d_in[10];
  const float* bd2  = (const float*)d_in[11];

  char* ws = (char*)d_ws;
  unsigned short* WA   = (unsigned short*)(ws + 0);          // 10,485,760
  unsigned short* WB   = (unsigned short*)(ws + 10485760);   // 16,777,216
  unsigned short* Wd1F = (unsigned short*)(ws + 27262976);   //  2,097,152
  unsigned short* Wd2F = (unsigned short*)(ws + 29360128);   //  4,194,304
  unsigned short* esw  = (unsigned short*)(ws + 33554432);   //  8,388,608
  float*          c1   = (float*)        (ws + 42467328);    //    262,144
  float*          c2   = (float*)        (ws + 42729472);    //    262,144
  unsigned short* seq  = (unsigned short*)(ws + 42991616);   // 33,554,432
  unsigned short* hd   = (unsigned short*)(ws + 76546048);   // 33,554,432 (scan scratch, then decoder)
  int*            bar  = (int*)          (ws + 110100480);   //      4,096
  float*          zpart = (float*)(ws + 76546048);           //  2 MB   (hd head)
  unsigned short* h1r  = (unsigned short*)(ws + 78643200);   //  4 MB ring (32 x 128KB)
  unsigned short* h2r  = (unsigned short*)(ws + 82837504);   //  4 MB ring (32 x 128KB)
  (void)in_sizes; (void)n_in; (void)out_size; (void)ws_size;

  // ---- setup ----
  k_pack_AB<<<2560, 256, 0, stream>>>(W1, U1, WA, 40, 256);
  k_pack_AB<<<4096, 256, 0, stream>>>(W2, U2, WB, 64, 1024);
  k_pack_D <<<512,  256, 0, stream>>>(Wd1, Wd1F, 64, 1024);
  k_pack_D <<<1024, 256, 0, stream>>>(Wd2, Wd2F, 128, 2048);
  k_embed  <<<2048, 256, 0, stream>>>(x, emb, esw);
  hipMemsetAsync(ws + 42467328, 0, 524288, stream);   // c1, c2
  hipMemsetAsync(ws + 78643200, 0, 131072, stream);   // h1 ring slot 0
  hipMemsetAsync(ws + 82837504, 0, 131072, stream);   // h2 ring slot 0
  hipMemsetAsync(ws + 110100480, 0, 4096, stream);    // barrier counters

  // ---- persistent scan: 257 phases, 1 dispatch, 256 CUs ----
  k_scan<<<256, 512, 0, stream>>>(esw, WA, WB, b1, b2, x,
                                  h1r, h2r, c1, c2, seq, zpart, bar);

  // ---- decoder ----
  k_dec<<<1024, 256, 0, stream>>>(seq, Wd1F, bd1, hd,    1024, 0);
  k_dec<<<2048, 256, 0, stream>>>(hd,  Wd2F, bd2, d_out, 2048, 1);
}